// Round 10
// baseline (152.216 us; speedup 1.0000x reference)
//
#include <hip/hip_runtime.h>

#define NM_ 1500000
#define NT_ 100000
#define NF_ 1500000
#define NTOT (NM_ + NT_ + NF_)
#define NBY_ 1024
#define TDv 0.9f

#define NB_  512          /* binning grid blocks (2 blocks/CU) */
#define BT_  1024         /* binning threads/block */
#define NIT  6            /* nodes cached per thread: 6*512*1024 >= NTOT */
#define SHY_ 5            /* tile = 32x32 bins */
#define TSY_ 32
#define NTILY_ 32                 /* y-tiles */
#define NTILES_ 1024              /* 32 x-tiles x 32 y-tiles (32x32 bins) */
#define NSTRIPE 2                 /* stripes of 16 tx-columns = 512 tiles */
#define STILES 512
#define BCAP 12                   /* LDS bucket slots/tile (mean 6.1, P(>12)~0.8%) */
#define OVCAP 128                 /* overflow side-buffer (mean ~13 items/block) */
#define CAP_M 4096u               /* movable bucket stride (mean ~3240, +15 sigma) */
#define CAP_F 512u                /* fixed-rect bucket stride (mean ~177, +25 sigma) */
#define QS 0.0009765625f          /* 1/1024 */
#define FXS 65536.0f              /* LDS fixed-point scale (2^16) */
#define FXSI 1.52587890625e-5f    /* 2^-16 */

// ---- movable/fill item: GLOBAL-coordinate fixed point, packed ONCE per node
//   w0 = xq(u10.10, 20 bits) | sxq(u2.10, 12 bits) << 20   (sizes <= 2.0 -> 2048)
//   w1 = yq | syq<<20
// Same uint2 is emitted to every tile the node touches (no per-item repack).
// Bit-identical to the old tile-local quantization: rint((x - tx*32 + 32)*1024)
// == rint(x*1024) - (tx-1)*32768 (exact integer shift).
// Zero item decodes to sx=sy=0 -> all weights 0 -> no-op.

// ---- fixed item (itemsF): OLD tile-local format (sizes up to 20.03 need 15b)
//   w0 = xq(u6.10)<<16 | yq(u6.10)   (coords offset by +32; range [-32,32))
//   w1 = sxq(u5.10)<<16 | syq(u5.10)
__device__ inline uint2 pack_item(float xl, float yl, float sx, float sy) {
    unsigned xq = min((unsigned)__builtin_rintf((xl + 32.0f) * 1024.0f), 65535u);
    unsigned yq = min((unsigned)__builtin_rintf((yl + 32.0f) * 1024.0f), 65535u);
    unsigned sxq = (unsigned)__builtin_rintf(sx * 1024.0f);
    unsigned syq = (unsigned)__builtin_rintf(sy * 1024.0f);
    uint2 r; r.x = (xq << 16) | yq; r.y = (sxq << 16) | syq; return r;
}

// movable item (global-coord format): fully-unrolled 3x3 (span <= 3 bins);
// zero-weight adds predicated off. Bin index within 32x32 tile: (bx<<5)+by.
__device__ inline void mov_3x3(uint2 v, unsigned* sm, float fbx, float fby) {
    float xl = (float)(v.x & 0xFFFFFu) * QS - fbx;   // tile-local
    float yl = (float)(v.y & 0xFFFFFu) * QS - fby;
    float sx = (float)(v.x >> 20) * QS;
    float sy = (float)(v.y >> 20) * QS;
    float xh = xl + sx, yh = yl + sy;
    int bx0 = (int)floorf(xl), by0 = (int)floorf(yl);
    #pragma unroll
    for (int dx = 0; dx < 3; ++dx) {
        int bx = bx0 + dx;
        float ox = fmaxf(fminf(xh, (float)(bx + 1)) - fmaxf(xl, (float)bx), 0.0f) * FXS;
        bool okx = ((unsigned)bx < 32u);
        int bxc = min(max(bx, 0), 31);
        #pragma unroll
        for (int dy = 0; dy < 3; ++dy) {
            int by = by0 + dy;
            float oy = fmaxf(fminf(yh, (float)(by + 1)) - fmaxf(yl, (float)by), 0.0f);
            float w = (okx && ((unsigned)by < 32u)) ? ox * oy : 0.0f;
            int byc = min(max(by, 0), 31);
            if (w != 0.0f)
                atomicAdd(&sm[(bxc << 5) + byc], (unsigned)__float2uint_rn(w));
        }
    }
}

// fixed rect via separable difference maps: <=16 point adds instead of
// walking the O(area) footprint. Signed entries ride in u32 two's-complement.
// A zero item (all fields 0) is a no-op (all predicates false).
__device__ inline void fix_rect_diff(uint2 v, unsigned* S, unsigned* U,
                                     unsigned* V, unsigned* W) {
    float xl = (float)(v.x >> 16) * QS - 32.0f;
    float yl = (float)(v.x & 0xffffu) * QS - 32.0f;
    float sx = (float)(v.y >> 16) * QS;
    float sy = (float)(v.y & 0xffffu) * QS;
    float xh = xl + sx, yh = yl + sy;
    int xlo = (int)floorf(xl), xhi = (int)floorf(xh);
    int ylo = (int)floorf(yl), yhi = (int)floorf(yh);
    float ax = fminf(xh, (float)(xlo + 1)) - xl;
    float bx = xh - (float)xhi;
    float ay = fminf(yh, (float)(ylo + 1)) - yl;
    float by = yh - (float)yhi;
    int xs = max(xlo + 1, 0), xe = min(xhi - 1, 31);
    int ys = max(ylo + 1, 0), ye = min(yhi - 1, 31);
    bool runx = (xs <= xe), runy = (ys <= ye);
    bool c_xlo = ((unsigned)xlo < 32u), c_xhi = ((unsigned)xhi < 32u);
    bool c_ylo = ((unsigned)ylo < 32u), c_yhi = ((unsigned)yhi < 32u);
    const float SC = TDv * FXS;
    if (c_xlo && c_ylo) atomicAdd(&S[(xlo << 5) + ylo], (unsigned)__float2int_rn(ax * ay * SC));
    if (c_xlo && c_yhi) atomicAdd(&S[(xlo << 5) + yhi], (unsigned)__float2int_rn(ax * by * SC));
    if (c_xhi && c_ylo) atomicAdd(&S[(xhi << 5) + ylo], (unsigned)__float2int_rn(bx * ay * SC));
    if (c_xhi && c_yhi) atomicAdd(&S[(xhi << 5) + yhi], (unsigned)__float2int_rn(bx * by * SC));
    if (runy) {
        int iax = __float2int_rn(ax * SC), ibx = __float2int_rn(bx * SC);
        if (c_xlo) {
            atomicAdd(&U[(xlo << 5) + ys], (unsigned)iax);
            if (ye < 31) atomicAdd(&U[(xlo << 5) + ye + 1], (unsigned)(-iax));
        }
        if (c_xhi) {
            atomicAdd(&U[(xhi << 5) + ys], (unsigned)ibx);
            if (ye < 31) atomicAdd(&U[(xhi << 5) + ye + 1], (unsigned)(-ibx));
        }
    }
    if (runx) {
        int iay = __float2int_rn(ay * SC), iby = __float2int_rn(by * SC);
        if (c_ylo) {
            atomicAdd(&V[(xs << 5) + ylo], (unsigned)iay);
            if (xe < 31) atomicAdd(&V[((xe + 1) << 5) + ylo], (unsigned)(-iay));
        }
        if (c_yhi) {
            atomicAdd(&V[(xs << 5) + yhi], (unsigned)iby);
            if (xe < 31) atomicAdd(&V[((xe + 1) << 5) + yhi], (unsigned)(-iby));
        }
    }
    if (runx && runy) {
        const int iSC = 58982;   /* round(TDv * FXS) */
        atomicAdd(&W[(xs << 5) + ys], (unsigned)iSC);
        if (ye < 31) atomicAdd(&W[(xs << 5) + ye + 1], (unsigned)(-iSC));
        if (xe < 31) {
            atomicAdd(&W[((xe + 1) << 5) + ys], (unsigned)(-iSC));
            if (ye < 31) atomicAdd(&W[((xe + 1) << 5) + ye + 1], (unsigned)iSC);
        }
    }
}

// ============== binning: fixed-cap LDS buckets + burst write-out ============
// R10: pack hoisted out of the walks. Node cache = packed item (2 regs) +
// span/flag word (1 reg) per node; stripe walk body is decode-span ->
// LDS-atomic -> 8B store, zero float ops. (R9 profile: bin_k VALUBusy 40%
// with per-item pack_item in the loop -- that VALU is the target.)
__global__ __launch_bounds__(BT_, 4) void
bin_k(const float* __restrict__ xs, const float* __restrict__ ys,
      const float* __restrict__ sxs, const float* __restrict__ sys,
      unsigned* __restrict__ gM, unsigned* __restrict__ gF,
      uint2* __restrict__ itemsM, uint2* __restrict__ itemsF) {
    __shared__ uint2 bucket[STILES * BCAP];          // 48 KB
    __shared__ unsigned scnt[STILES], sgb[STILES];   // 4 KB
    __shared__ unsigned lhF[NTILES_];                // 4 KB (base-cursor)
    __shared__ uint2 ovf_it[OVCAP];                  // 1 KB
    __shared__ unsigned short ovf_tl[OVCAP];         // 256 B
    __shared__ unsigned sovf_n;
    int tid = threadIdx.x;
    int t0 = blockIdx.x * BT_ + tid;
    // ---- node cache: packed once (R5 proved reloads double FETCH) ----
    // spn: txa(5) txb(5) tya(5) tyb(5) val(1) fixc(1)
    uint2 pit[NIT];
    unsigned spn[NIT];
    #pragma unroll
    for (int k = 0; k < NIT; ++k) {
        int i = t0 + k * (NB_ * BT_);
        bool v = (i < NTOT);
        int ii = v ? i : 0;
        float xi = xs[ii], yi = ys[ii], sxi = sxs[ii], syi = sys[ii];
        bool fx = (i >= NM_) && (i < NM_ + NT_);
        unsigned txa = (unsigned)((int)xi >> 5), txb = (unsigned)((int)(xi + sxi) >> 5);
        unsigned tya = (unsigned)((int)yi >> SHY_), tyb = (unsigned)((int)(yi + syi) >> SHY_);
        unsigned xq = (unsigned)__builtin_rintf(xi * 1024.0f);
        unsigned yq = (unsigned)__builtin_rintf(yi * 1024.0f);
        unsigned sxq = (unsigned)__builtin_rintf(sxi * 1024.0f);
        unsigned syq = (unsigned)__builtin_rintf(syi * 1024.0f);
        pit[k].x = xq | ((sxq & 0xFFFu) << 20);      // sxq<=2048 for movable/fill
        pit[k].y = yq | ((syq & 0xFFFu) << 20);
        spn[k] = txa | (txb << 5) | (tya << 10) | (tyb << 15)
               | ((unsigned)v << 20) | ((unsigned)fx << 21);
    }
    // ---- fixed-rect path: direct scatter (~200 nodes/block) ----
    for (int j = tid; j < NTILES_; j += BT_) lhF[j] = 0u;
    __syncthreads();
    #pragma unroll
    for (int k = 0; k < NIT; ++k) if ((spn[k] & (3u << 20)) == (3u << 20)) {
        unsigned s = spn[k];
        unsigned txa = s & 31u, txb = (s >> 5) & 31u, tya = (s >> 10) & 31u, tyb = (s >> 15) & 31u;
        for (unsigned tx = txa; tx <= txb; ++tx)
            for (unsigned ty = tya; ty <= tyb; ++ty) atomicAdd(&lhF[tx * NTILY_ + ty], 1u);
    }
    __syncthreads();
    for (int j = tid; j < NTILES_; j += BT_) {
        unsigned c = lhF[j];
        lhF[j] = c ? atomicAdd(&gF[j], c) : 0u;      // becomes base+cursor
    }
    __syncthreads();
    #pragma unroll
    for (int k = 0; k < NIT; ++k) if ((spn[k] & (3u << 20)) == (3u << 20)) {
        int i = t0 + k * (NB_ * BT_);
        float xi = xs[i], yi = ys[i], sxi = sxs[i], syi = sys[i];  // L3-warm reload
        unsigned s = spn[k];
        unsigned txa = s & 31u, txb = (s >> 5) & 31u, tya = (s >> 10) & 31u, tyb = (s >> 15) & 31u;
        for (unsigned tx = txa; tx <= txb; ++tx)
            for (unsigned ty = tya; ty <= tyb; ++ty) {
                int tl = (int)(tx * NTILY_ + ty);
                unsigned r = atomicAdd(&lhF[tl], 1u);
                if (r < CAP_F)
                    itemsF[(size_t)tl * CAP_F + r] =
                        pack_item(xi - (float)(tx * 32), yi - (float)(ty * TSY_), sxi, syi);
            }
    }
    // ---- movable path: 2 stripes (tx 0-15, 16-31), fixed-cap buckets ----
    for (int sp = 0; sp < NSTRIPE; ++sp) {
        __syncthreads();                   // previous stripe's LDS reusable
        if (tid < STILES) scnt[tid] = 0u;
        if (tid == 0) sovf_n = 0u;
        __syncthreads();
        // single stage walk: no pack, no float ops -- just atomic + 8B store
        #pragma unroll
        for (int k = 0; k < NIT; ++k) if ((spn[k] & (3u << 20)) == (1u << 20)) {
            unsigned s = spn[k];
            int txa = (int)(s & 31u), txb = (int)((s >> 5) & 31u);
            int tya = (int)((s >> 10) & 31u), tyb = (int)((s >> 15) & 31u);
            int lo = max(txa, sp * 16), hi = min(txb, sp * 16 + 15);
            uint2 it = pit[k];             // same item for every tile
            for (int tx = lo; tx <= hi; ++tx)
                for (int ty = tya; ty <= tyb; ++ty) {
                    unsigned tl_l = (unsigned)(((tx & 15) << 5) + ty);
                    unsigned c = atomicAdd(&scnt[tl_l], 1u);
                    if (c < BCAP) bucket[tl_l * BCAP + c] = it;
                    else {
                        unsigned o = atomicAdd(&sovf_n, 1u);
                        if (o < OVCAP) { ovf_it[o] = it; ovf_tl[o] = (unsigned short)tl_l; }
                    }
                }
        }
        __syncthreads();
        // bases: one global atomic per non-empty tile (no prefix scan)
        if (tid < STILES) {
            unsigned c = scnt[tid];
            sgb[tid] = c ? atomicAdd(&gM[(sp << 9) + tid], c) : 0u;
        }
        __syncthreads();
        // burst write-out: consecutive slots -> coalesced contiguous stores
        unsigned nov = min(sovf_n, (unsigned)OVCAP);
        for (int s = tid; s < STILES * BCAP; s += BT_) {
            int tl = s / BCAP, sl = s - tl * BCAP;
            if ((unsigned)sl < min(scnt[tl], (unsigned)BCAP)) {
                unsigned g = sgb[tl] + (unsigned)sl;
                if (g < CAP_M)
                    itemsM[(size_t)((sp << 9) + tl) * CAP_M + g] = bucket[s];
            }
        }
        // overflow: atomicSub hands out slots cnt-1 .. BCAP (ends at BCAP,
        // so the concurrent min(scnt,BCAP) reads above stay correct)
        for (unsigned o = tid; o < nov; o += BT_) {
            unsigned tl = ovf_tl[o];
            unsigned c = atomicSub(&scnt[tl], 1u) - 1u;
            unsigned g = sgb[tl] + c;
            if (g < CAP_M)
                itemsM[(size_t)((sp << 9) + tl) * CAP_M + g] = ovf_it[o];
        }
    }
}

// ---------------------------------------------------------------- accum ----
// R8's proven 256-thread form (R9's 512-thread + folded reduce was -3 us:
// accum is item-load latency-bound, not occupancy-starved). Tail: plain
// stores to partials[] (no same-address global atomics -- R3's 3x win).
__global__ __launch_bounds__(256, 4) void
accum2_k(const unsigned* __restrict__ gM, const unsigned* __restrict__ gF,
         const uint2* __restrict__ itemsM, const uint2* __restrict__ itemsF,
         const unsigned char* __restrict__ pm, float* __restrict__ partials) {
    __shared__ unsigned sm[1024], U[1024], V[1024], W[1024];
    int t = blockIdx.x;
    int baseX = (t >> 5) * 32, baseY = (t & 31) * TSY_;
    float fbx = (float)baseX, fby = (float)baseY;
    unsigned nm = min(gM[t], CAP_M), nf = min(gF[t], CAP_F);
    const uint2* im = itemsM + (size_t)t * CAP_M;
    const uint2* fi = itemsF + (size_t)t * CAP_F;

    // ---- issue all loads up front (independent -> high MLP) ----
    uint2 itv[16];
    #pragma unroll
    for (int j = 0; j < 8; ++j) {
        unsigned k = threadIdx.x * 2u + (unsigned)j * 512u;
        uint4 u = make_uint4(0u, 0u, 0u, 0u);
        if (k < nm) u = *(const uint4*)(im + k);       // 16B aligned: k even, im 16B-aligned
        bool h2 = (k + 1u < nm);
        itv[2 * j].x = u.x;           itv[2 * j].y = u.y;
        itv[2 * j + 1].x = h2 ? u.z : 0u;
        itv[2 * j + 1].y = h2 ? u.w : 0u;
    }
    uint2 fv0 = make_uint2(0u, 0u), fv1 = make_uint2(0u, 0u);  // zero item = no-op
    {
        unsigned k = threadIdx.x * 2u;
        uint4 u = make_uint4(0u, 0u, 0u, 0u);
        if (k < nf) u = *(const uint4*)(fi + k);       // nf <= 512 = 2*256
        fv0.x = u.x; fv0.y = u.y;
        if (k + 1u < nf) { fv1.x = u.z; fv1.y = u.w; }
    }
    int j0 = threadIdx.x, j1 = j0 + 256, j2 = j0 + 512, j3 = j0 + 768;
    unsigned char p0 = pm[(size_t)(baseX + (j0 >> 5)) * NBY_ + baseY + (j0 & 31)];
    unsigned char p1 = pm[(size_t)(baseX + (j1 >> 5)) * NBY_ + baseY + (j1 & 31)];
    unsigned char p2 = pm[(size_t)(baseX + (j2 >> 5)) * NBY_ + baseY + (j2 & 31)];
    unsigned char p3 = pm[(size_t)(baseX + (j3 >> 5)) * NBY_ + baseY + (j3 & 31)];

    for (int j = threadIdx.x; j < 1024; j += 256) { sm[j] = 0u; U[j] = 0u; V[j] = 0u; W[j] = 0u; }
    __syncthreads();

    // phase A: movable rects from registers (global-coord decode)
    #pragma unroll
    for (int j = 0; j < 16; ++j) mov_3x3(itv[j], sm, fbx, fby);
    // phase B: fixed rects, per-lane difference-map scatter (O(1) per rect)
    fix_rect_diff(fv0, sm, U, V, W);
    fix_rect_diff(fv1, sm, U, V, W);
    __syncthreads();

    // reconstruction pass 1: per-bx prefix along y; sm += Py(U); V += Py(W)
    if (threadIdx.x < 32) {
        int bx = threadIdx.x;
        unsigned u = 0, w = 0;
        for (int by = 0; by < 32; ++by) {
            int idx = (bx << 5) + by;
            u += U[idx]; w += W[idx];
            sm[idx] += u;
            V[idx] += w;
        }
    }
    __syncthreads();
    // pass 2: per-by prefix along x of (V + Py(W)) added into sm
    if (threadIdx.x < 32) {
        int by = threadIdx.x;
        unsigned tacc = 0;
        for (int bx = 0; bx < 32; ++bx) {
            int idx = (bx << 5) + by;
            tacc += V[idx];
            sm[idx] += tacc;
        }
    }
    __syncthreads();

    // tail: reduce 1024 bins -> (S, M), plain store (NO global atomics)
    float d0 = (float)sm[j0] * FXSI;
    if (p0) d0 = TDv;
    float d1 = (float)sm[j1] * FXSI;
    if (p1) d1 = TDv;
    float d2 = (float)sm[j2] * FXSI;
    if (p2) d2 = TDv;
    float d3 = (float)sm[j3] * FXSI;
    if (p3) d3 = TDv;
    float acc = fmaxf(d0 - TDv, 0.0f) + fmaxf(d1 - TDv, 0.0f)
              + fmaxf(d2 - TDv, 0.0f) + fmaxf(d3 - TDv, 0.0f);
    float mx = fmaxf(fmaxf(d0, d1), fmaxf(d2, d3));
    int lane = threadIdx.x & 63, wv = threadIdx.x >> 6;
    for (int off2 = 32; off2 > 0; off2 >>= 1) {
        acc += __shfl_down(acc, off2, 64);
        mx = fmaxf(mx, __shfl_down(mx, off2, 64));
    }
    __shared__ float ssum[4], smax[4];
    if (lane == 0) { ssum[wv] = acc; smax[wv] = mx; }
    __syncthreads();
    if (threadIdx.x == 0) {
        float S = ssum[0], M = smax[0];
        for (int w2 = 1; w2 < 4; ++w2) { S += ssum[w2]; M = fmaxf(M, smax[w2]); }
        partials[2 * t] = S;
        partials[2 * t + 1] = M;
    }
}

// -------------------------------------------------------- final reduce ----
// single block: 1024 (S, M) pairs -> out[0..1]; also removes memset(out).
__global__ __launch_bounds__(1024) void
reduce_k(const float* __restrict__ partials, float* __restrict__ out) {
    int t = threadIdx.x;
    float S = partials[2 * t];
    float M = partials[2 * t + 1];
    for (int off2 = 32; off2 > 0; off2 >>= 1) {
        S += __shfl_down(S, off2, 64);
        M = fmaxf(M, __shfl_down(M, off2, 64));
    }
    __shared__ float sS[16], sM[16];
    int lane = t & 63, wv = t >> 6;
    if (lane == 0) { sS[wv] = S; sM[wv] = M; }
    __syncthreads();
    if (t == 0) {
        float a = sS[0], b = sM[0];
        for (int w2 = 1; w2 < 16; ++w2) { a += sS[w2]; b = fmaxf(b, sM[w2]); }
        out[0] = a;           // density_cost
        out[1] = b;           // max_density (bin_area = 1)
    }
}

extern "C" void kernel_launch(void* const* d_in, const int* in_sizes, int n_in,
                              void* d_out, int out_size, void* d_ws, size_t ws_size,
                              hipStream_t stream) {
    const float* pos = (const float*)d_in[0];
    const float* xs = pos;
    const float* ys = pos + NTOT;
    const float* sxs = (const float*)d_in[1];
    const float* sys = (const float*)d_in[2];
    const unsigned char* pm = (const unsigned char*)d_in[5];
    float* out = (float*)d_out;

    // layout: counters + fixed-stride buckets + partials (36.02 MB; ws >= 60.85 MB)
    unsigned* gM = (unsigned*)d_ws;                                  // 4 KB
    unsigned* gF = gM + NTILES_;                                     // 4 KB
    uint2* itemsM = (uint2*)(gF + NTILES_);                          // 32 MB
    uint2* itemsF = itemsM + (size_t)NTILES_ * CAP_M;                // 4 MB
    float* partials = (float*)(itemsF + (size_t)NTILES_ * CAP_F);    // 8 KB

    hipMemsetAsync(gM, 0, 2 * NTILES_ * sizeof(unsigned), stream);
    bin_k<<<NB_, BT_, 0, stream>>>(xs, ys, sxs, sys, gM, gF, itemsM, itemsF);
    accum2_k<<<NTILES_, 256, 0, stream>>>(gM, gF, itemsM, itemsF, pm, partials);
    reduce_k<<<1, 1024, 0, stream>>>(partials, out);
}

// Round 11
// 145.025 us; speedup vs baseline: 1.0496x; 1.0496x over previous
//
#include <hip/hip_runtime.h>

#define NM_ 1500000
#define NT_ 100000
#define NF_ 1500000
#define NTOT (NM_ + NT_ + NF_)
#define NBY_ 1024
#define TDv 0.9f

#define NB_  512          /* binning grid blocks (2 blocks/CU) */
#define BT_  1024         /* binning threads/block */
#define NIT  6            /* nodes cached per thread: 6*512*1024 >= NTOT */
#define SHY_ 5            /* tile = 32x32 bins */
#define TSY_ 32
#define NTILY_ 32                 /* y-tiles */
#define NTILES_ 1024              /* 32 x-tiles x 32 y-tiles (32x32 bins) */
#define NSTRIPE 2                 /* stripes of 16 tx-columns = 512 tiles */
#define STILES 512
#define BCAP 12                   /* LDS bucket slots/tile (mean 6.1, P(>12)~0.8%) */
#define OVCAP 128                 /* overflow side-buffer (mean ~13 items/block) */
#define CAP_M 4096u               /* movable bucket stride (mean ~3240, +15 sigma) */
#define CAP_F 512u                /* fixed-rect bucket stride (mean ~177, +25 sigma) */
#define QS 0.0009765625f          /* 1/1024 */
#define FXS 65536.0f              /* LDS fixed-point scale (2^16) */
#define FXSI 1.52587890625e-5f    /* 2^-16 */

// universal 8B item: tile-local fixed point
// w0 = xq(u6.10)<<16 | yq(u6.10)   (coords offset by +32; range [-32,32))
// w1 = sxq(u5.10)<<16 | syq(u5.10) (sizes up to 20.03 fit 15 bits)
__device__ inline uint2 pack_item(float xl, float yl, float sx, float sy) {
    unsigned xq = min((unsigned)__builtin_rintf((xl + 32.0f) * 1024.0f), 65535u);
    unsigned yq = min((unsigned)__builtin_rintf((yl + 32.0f) * 1024.0f), 65535u);
    unsigned sxq = (unsigned)__builtin_rintf(sx * 1024.0f);
    unsigned syq = (unsigned)__builtin_rintf(sy * 1024.0f);
    uint2 r; r.x = (xq << 16) | yq; r.y = (sxq << 16) | syq; return r;
}

// movable item: fully-unrolled 3x3 (movable size <= ~2 -> span <= 3 bins);
// zero-weight adds predicated off. Bin index within 32x32 tile: (bx<<5)+by.
__device__ inline void mov_3x3(uint2 v, unsigned* sm) {
    float xl = (float)(v.x >> 16) * QS - 32.0f;
    float yl = (float)(v.x & 0xffffu) * QS - 32.0f;
    float sx = (float)(v.y >> 16) * QS;
    float sy = (float)(v.y & 0xffffu) * QS;
    float xh = xl + sx, yh = yl + sy;
    int bx0 = (int)floorf(xl), by0 = (int)floorf(yl);
    #pragma unroll
    for (int dx = 0; dx < 3; ++dx) {
        int bx = bx0 + dx;
        float ox = fmaxf(fminf(xh, (float)(bx + 1)) - fmaxf(xl, (float)bx), 0.0f) * FXS;
        bool okx = ((unsigned)bx < 32u);
        int bxc = min(max(bx, 0), 31);
        #pragma unroll
        for (int dy = 0; dy < 3; ++dy) {
            int by = by0 + dy;
            float oy = fmaxf(fminf(yh, (float)(by + 1)) - fmaxf(yl, (float)by), 0.0f);
            float w = (okx && ((unsigned)by < 32u)) ? ox * oy : 0.0f;
            int byc = min(max(by, 0), 31);
            if (w != 0.0f)
                atomicAdd(&sm[(bxc << 5) + byc], (unsigned)__float2uint_rn(w));
        }
    }
}

// fixed rect via separable difference maps: <=16 point adds instead of
// walking the O(area) footprint. Signed entries ride in u32 two's-complement.
// A zero item (all fields 0) is a no-op (all predicates false).
__device__ inline void fix_rect_diff(uint2 v, unsigned* S, unsigned* U,
                                     unsigned* V, unsigned* W) {
    float xl = (float)(v.x >> 16) * QS - 32.0f;
    float yl = (float)(v.x & 0xffffu) * QS - 32.0f;
    float sx = (float)(v.y >> 16) * QS;
    float sy = (float)(v.y & 0xffffu) * QS;
    float xh = xl + sx, yh = yl + sy;
    int xlo = (int)floorf(xl), xhi = (int)floorf(xh);
    int ylo = (int)floorf(yl), yhi = (int)floorf(yh);
    float ax = fminf(xh, (float)(xlo + 1)) - xl;
    float bx = xh - (float)xhi;
    float ay = fminf(yh, (float)(ylo + 1)) - yl;
    float by = yh - (float)yhi;
    int xs = max(xlo + 1, 0), xe = min(xhi - 1, 31);
    int ys = max(ylo + 1, 0), ye = min(yhi - 1, 31);
    bool runx = (xs <= xe), runy = (ys <= ye);
    bool c_xlo = ((unsigned)xlo < 32u), c_xhi = ((unsigned)xhi < 32u);
    bool c_ylo = ((unsigned)ylo < 32u), c_yhi = ((unsigned)yhi < 32u);
    const float SC = TDv * FXS;
    if (c_xlo && c_ylo) atomicAdd(&S[(xlo << 5) + ylo], (unsigned)__float2int_rn(ax * ay * SC));
    if (c_xlo && c_yhi) atomicAdd(&S[(xlo << 5) + yhi], (unsigned)__float2int_rn(ax * by * SC));
    if (c_xhi && c_ylo) atomicAdd(&S[(xhi << 5) + ylo], (unsigned)__float2int_rn(bx * ay * SC));
    if (c_xhi && c_yhi) atomicAdd(&S[(xhi << 5) + yhi], (unsigned)__float2int_rn(bx * by * SC));
    if (runy) {
        int iax = __float2int_rn(ax * SC), ibx = __float2int_rn(bx * SC);
        if (c_xlo) {
            atomicAdd(&U[(xlo << 5) + ys], (unsigned)iax);
            if (ye < 31) atomicAdd(&U[(xlo << 5) + ye + 1], (unsigned)(-iax));
        }
        if (c_xhi) {
            atomicAdd(&U[(xhi << 5) + ys], (unsigned)ibx);
            if (ye < 31) atomicAdd(&U[(xhi << 5) + ye + 1], (unsigned)(-ibx));
        }
    }
    if (runx) {
        int iay = __float2int_rn(ay * SC), iby = __float2int_rn(by * SC);
        if (c_ylo) {
            atomicAdd(&V[(xs << 5) + ylo], (unsigned)iay);
            if (xe < 31) atomicAdd(&V[((xe + 1) << 5) + ylo], (unsigned)(-iay));
        }
        if (c_yhi) {
            atomicAdd(&V[(xs << 5) + yhi], (unsigned)iby);
            if (xe < 31) atomicAdd(&V[((xe + 1) << 5) + yhi], (unsigned)(-iby));
        }
    }
    if (runx && runy) {
        const int iSC = 58982;   /* round(TDv * FXS) */
        atomicAdd(&W[(xs << 5) + ys], (unsigned)iSC);
        if (ye < 31) atomicAdd(&W[(xs << 5) + ye + 1], (unsigned)(-iSC));
        if (xe < 31) {
            atomicAdd(&W[((xe + 1) << 5) + ys], (unsigned)(-iSC));
            if (ye < 31) atomicAdd(&W[((xe + 1) << 5) + ye + 1], (unsigned)iSC);
        }
    }
}

// ============== binning: fixed-cap LDS buckets + burst write-out ============
// R8 structure (proven best, 148.2 us end-to-end): burst-write keeps WRITE
// at ~40 MB (vs 96 MB direct scatter, R7 finding) at ~R4 walk cost.
// R10 falsified VALU as the limiter; R6 falsified run-length; remaining 42 us
// is the LDS-atomic + barrier critical path of grouping itself.
__global__ __launch_bounds__(BT_, 4) void
bin_k(const float* __restrict__ xs, const float* __restrict__ ys,
      const float* __restrict__ sxs, const float* __restrict__ sys,
      unsigned* __restrict__ gM, unsigned* __restrict__ gF,
      uint2* __restrict__ itemsM, uint2* __restrict__ itemsF) {
    __shared__ uint2 bucket[STILES * BCAP];          // 48 KB
    __shared__ unsigned scnt[STILES], sgb[STILES];   // 4 KB
    __shared__ unsigned lhF[NTILES_];                // 4 KB (base-cursor)
    __shared__ uint2 ovf_it[OVCAP];                  // 1 KB
    __shared__ unsigned short ovf_tl[OVCAP];         // 256 B
    __shared__ unsigned sovf_n;
    int tid = threadIdx.x;
    int t0 = blockIdx.x * BT_ + tid;
    // ---- register node cache (R5 proved reloads double FETCH) ----
    float cx[NIT], cy[NIT], csx[NIT], csy[NIT];
    bool val[NIT], fixc[NIT];
    #pragma unroll
    for (int k = 0; k < NIT; ++k) {
        int i = t0 + k * (NB_ * BT_);
        val[k] = (i < NTOT);
        int ii = val[k] ? i : 0;
        cx[k] = xs[ii]; cy[k] = ys[ii]; csx[k] = sxs[ii]; csy[k] = sys[ii];
        fixc[k] = (i >= NM_) && (i < NM_ + NT_);
    }
    // ---- fixed-rect path: direct scatter (~350 items/block) ----
    for (int j = tid; j < NTILES_; j += BT_) lhF[j] = 0u;
    __syncthreads();
    #pragma unroll
    for (int k = 0; k < NIT; ++k) if (val[k] && fixc[k]) {
        int txa = (int)cx[k] >> 5, txb = (int)(cx[k] + csx[k]) >> 5;
        int tya = (int)cy[k] >> SHY_, tyb = (int)(cy[k] + csy[k]) >> SHY_;
        for (int tx = txa; tx <= txb; ++tx)
            for (int ty = tya; ty <= tyb; ++ty) atomicAdd(&lhF[tx * NTILY_ + ty], 1u);
    }
    __syncthreads();
    for (int j = tid; j < NTILES_; j += BT_) {
        unsigned c = lhF[j];
        lhF[j] = c ? atomicAdd(&gF[j], c) : 0u;      // becomes base+cursor
    }
    __syncthreads();
    #pragma unroll
    for (int k = 0; k < NIT; ++k) if (val[k] && fixc[k]) {
        float xi = cx[k], yi = cy[k], sxi = csx[k], syi = csy[k];
        int txa = (int)xi >> 5, txb = (int)(xi + sxi) >> 5;
        int tya = (int)yi >> SHY_, tyb = (int)(yi + syi) >> SHY_;
        for (int tx = txa; tx <= txb; ++tx)
            for (int ty = tya; ty <= tyb; ++ty) {
                int tl = tx * NTILY_ + ty;
                unsigned r = atomicAdd(&lhF[tl], 1u);  // global slot in bucket
                if (r < CAP_F)
                    itemsF[(size_t)tl * CAP_F + r] =
                        pack_item(xi - (float)(tx * 32), yi - (float)(ty * TSY_), sxi, syi);
            }
    }
    // ---- movable path: 2 stripes (tx 0-15, 16-31), fixed-cap buckets ----
    for (int sp = 0; sp < NSTRIPE; ++sp) {
        __syncthreads();                   // previous stripe's LDS reusable
        if (tid < STILES) scnt[tid] = 0u;
        if (tid == 0) sovf_n = 0u;
        __syncthreads();
        // single stage walk (no pre-histogram)
        #pragma unroll
        for (int k = 0; k < NIT; ++k) if (val[k] && !fixc[k]) {
            float xi = cx[k], yi = cy[k], sxi = csx[k], syi = csy[k];
            int txa = (int)xi >> 5, txb = (int)(xi + sxi) >> 5;
            int tya = (int)yi >> SHY_, tyb = (int)(yi + syi) >> SHY_;
            int lo = max(txa, sp * 16), hi = min(txb, sp * 16 + 15);
            for (int tx = lo; tx <= hi; ++tx)
                for (int ty = tya; ty <= tyb; ++ty) {
                    unsigned tl_l = (unsigned)(((tx & 15) << 5) + ty);
                    uint2 it = pack_item(xi - (float)(tx * 32),
                                         yi - (float)(ty * TSY_), sxi, syi);
                    unsigned c = atomicAdd(&scnt[tl_l], 1u);
                    if (c < BCAP) bucket[tl_l * BCAP + c] = it;
                    else {
                        unsigned o = atomicAdd(&sovf_n, 1u);
                        if (o < OVCAP) { ovf_it[o] = it; ovf_tl[o] = (unsigned short)tl_l; }
                    }
                }
        }
        __syncthreads();
        // bases: one global atomic per non-empty tile (no prefix scan)
        if (tid < STILES) {
            unsigned c = scnt[tid];
            sgb[tid] = c ? atomicAdd(&gM[(sp << 9) + tid], c) : 0u;
        }
        __syncthreads();
        // burst write-out: consecutive slots -> coalesced contiguous stores
        unsigned nov = min(sovf_n, (unsigned)OVCAP);
        for (int s = tid; s < STILES * BCAP; s += BT_) {
            int tl = s / BCAP, sl = s - tl * BCAP;
            if ((unsigned)sl < min(scnt[tl], (unsigned)BCAP)) {
                unsigned g = sgb[tl] + (unsigned)sl;
                if (g < CAP_M)
                    itemsM[(size_t)((sp << 9) + tl) * CAP_M + g] = bucket[s];
            }
        }
        // overflow: atomicSub hands out slots cnt-1 .. BCAP (ends at BCAP,
        // so the concurrent min(scnt,BCAP) reads above stay correct)
        for (unsigned o = tid; o < nov; o += BT_) {
            unsigned tl = ovf_tl[o];
            unsigned c = atomicSub(&scnt[tl], 1u) - 1u;
            unsigned g = sgb[tl] + c;
            if (g < CAP_M)
                itemsM[(size_t)((sp << 9) + tl) * CAP_M + g] = ovf_it[o];
        }
    }
}

// ---------------------------------------------------------------- accum ----
// 1024 blocks x 256 threads, 16KB LDS -> 4 blocks/CU: whole grid co-resident.
// Tail: plain stores to partials[] (no global atomics -- R3's 3x win).
// R1 (MLP) and R9 (512-thr + folded reduce) both falsified as levers.
__global__ __launch_bounds__(256, 4) void
accum2_k(const unsigned* __restrict__ gM, const unsigned* __restrict__ gF,
         const uint2* __restrict__ itemsM, const uint2* __restrict__ itemsF,
         const unsigned char* __restrict__ pm, float* __restrict__ partials) {
    __shared__ unsigned sm[1024], U[1024], V[1024], W[1024];
    int t = blockIdx.x;
    int baseX = (t >> 5) * 32, baseY = (t & 31) * TSY_;
    unsigned nm = min(gM[t], CAP_M), nf = min(gF[t], CAP_F);
    const uint2* im = itemsM + (size_t)t * CAP_M;
    const uint2* fi = itemsF + (size_t)t * CAP_F;

    // ---- issue all loads up front (independent -> high MLP) ----
    uint2 itv[16];
    #pragma unroll
    for (int j = 0; j < 8; ++j) {
        unsigned k = threadIdx.x * 2u + (unsigned)j * 512u;
        uint4 u = make_uint4(0u, 0u, 0u, 0u);
        if (k < nm) u = *(const uint4*)(im + k);       // 16B aligned: k even, im 32KB-aligned
        bool h2 = (k + 1u < nm);
        itv[2 * j].x = u.x;           itv[2 * j].y = u.y;
        itv[2 * j + 1].x = h2 ? u.z : 0u;
        itv[2 * j + 1].y = h2 ? u.w : 0u;
    }
    uint2 fv0 = make_uint2(0u, 0u), fv1 = make_uint2(0u, 0u);  // zero item = no-op
    {
        unsigned k = threadIdx.x * 2u;
        uint4 u = make_uint4(0u, 0u, 0u, 0u);
        if (k < nf) u = *(const uint4*)(fi + k);       // nf <= 512 = 2*256
        fv0.x = u.x; fv0.y = u.y;
        if (k + 1u < nf) { fv1.x = u.z; fv1.y = u.w; }
    }
    int j0 = threadIdx.x, j1 = j0 + 256, j2 = j0 + 512, j3 = j0 + 768;
    unsigned char p0 = pm[(size_t)(baseX + (j0 >> 5)) * NBY_ + baseY + (j0 & 31)];
    unsigned char p1 = pm[(size_t)(baseX + (j1 >> 5)) * NBY_ + baseY + (j1 & 31)];
    unsigned char p2 = pm[(size_t)(baseX + (j2 >> 5)) * NBY_ + baseY + (j2 & 31)];
    unsigned char p3 = pm[(size_t)(baseX + (j3 >> 5)) * NBY_ + baseY + (j3 & 31)];

    for (int j = threadIdx.x; j < 1024; j += 256) { sm[j] = 0u; U[j] = 0u; V[j] = 0u; W[j] = 0u; }
    __syncthreads();

    // phase A: movable rects from registers
    #pragma unroll
    for (int j = 0; j < 16; ++j) mov_3x3(itv[j], sm);
    // phase B: fixed rects, per-lane difference-map scatter (O(1) per rect)
    fix_rect_diff(fv0, sm, U, V, W);
    fix_rect_diff(fv1, sm, U, V, W);
    __syncthreads();

    // reconstruction pass 1: per-bx prefix along y; sm += Py(U); V += Py(W)
    if (threadIdx.x < 32) {
        int bx = threadIdx.x;
        unsigned u = 0, w = 0;
        for (int by = 0; by < 32; ++by) {
            int idx = (bx << 5) + by;
            u += U[idx]; w += W[idx];
            sm[idx] += u;
            V[idx] += w;
        }
    }
    __syncthreads();
    // pass 2: per-by prefix along x of (V + Py(W)) added into sm
    if (threadIdx.x < 32) {
        int by = threadIdx.x;
        unsigned tacc = 0;
        for (int bx = 0; bx < 32; ++bx) {
            int idx = (bx << 5) + by;
            tacc += V[idx];
            sm[idx] += tacc;
        }
    }
    __syncthreads();

    // tail: reduce 1024 bins -> (S, M), plain store (NO global atomics)
    float d0 = (float)sm[j0] * FXSI;
    if (p0) d0 = TDv;
    float d1 = (float)sm[j1] * FXSI;
    if (p1) d1 = TDv;
    float d2 = (float)sm[j2] * FXSI;
    if (p2) d2 = TDv;
    float d3 = (float)sm[j3] * FXSI;
    if (p3) d3 = TDv;
    float acc = fmaxf(d0 - TDv, 0.0f) + fmaxf(d1 - TDv, 0.0f)
              + fmaxf(d2 - TDv, 0.0f) + fmaxf(d3 - TDv, 0.0f);
    float mx = fmaxf(fmaxf(d0, d1), fmaxf(d2, d3));
    int lane = threadIdx.x & 63, wv = threadIdx.x >> 6;
    for (int off2 = 32; off2 > 0; off2 >>= 1) {
        acc += __shfl_down(acc, off2, 64);
        mx = fmaxf(mx, __shfl_down(mx, off2, 64));
    }
    __shared__ float ssum[4], smax[4];
    if (lane == 0) { ssum[wv] = acc; smax[wv] = mx; }
    __syncthreads();
    if (threadIdx.x == 0) {
        float S = ssum[0], M = smax[0];
        for (int w2 = 1; w2 < 4; ++w2) { S += ssum[w2]; M = fmaxf(M, smax[w2]); }
        partials[2 * t] = S;
        partials[2 * t + 1] = M;
    }
}

// -------------------------------------------------------- final reduce ----
// single block: 1024 (S, M) pairs -> out[0..1]; also removes memset(out).
__global__ __launch_bounds__(1024) void
reduce_k(const float* __restrict__ partials, float* __restrict__ out) {
    int t = threadIdx.x;
    float S = partials[2 * t];
    float M = partials[2 * t + 1];
    for (int off2 = 32; off2 > 0; off2 >>= 1) {
        S += __shfl_down(S, off2, 64);
        M = fmaxf(M, __shfl_down(M, off2, 64));
    }
    __shared__ float sS[16], sM[16];
    int lane = t & 63, wv = t >> 6;
    if (lane == 0) { sS[wv] = S; sM[wv] = M; }
    __syncthreads();
    if (t == 0) {
        float a = sS[0], b = sM[0];
        for (int w2 = 1; w2 < 16; ++w2) { a += sS[w2]; b = fmaxf(b, sM[w2]); }
        out[0] = a;           // density_cost
        out[1] = b;           // max_density (bin_area = 1)
    }
}

extern "C" void kernel_launch(void* const* d_in, const int* in_sizes, int n_in,
                              void* d_out, int out_size, void* d_ws, size_t ws_size,
                              hipStream_t stream) {
    const float* pos = (const float*)d_in[0];
    const float* xs = pos;
    const float* ys = pos + NTOT;
    const float* sxs = (const float*)d_in[1];
    const float* sys = (const float*)d_in[2];
    const unsigned char* pm = (const unsigned char*)d_in[5];
    float* out = (float*)d_out;

    // layout: counters + fixed-stride buckets + partials (36.02 MB; ws >= 60.85 MB)
    unsigned* gM = (unsigned*)d_ws;                                  // 4 KB
    unsigned* gF = gM + NTILES_;                                     // 4 KB
    uint2* itemsM = (uint2*)(gF + NTILES_);                          // 32 MB
    uint2* itemsF = itemsM + (size_t)NTILES_ * CAP_M;                // 4 MB
    float* partials = (float*)(itemsF + (size_t)NTILES_ * CAP_F);    // 8 KB

    hipMemsetAsync(gM, 0, 2 * NTILES_ * sizeof(unsigned), stream);
    bin_k<<<NB_, BT_, 0, stream>>>(xs, ys, sxs, sys, gM, gF, itemsM, itemsF);
    accum2_k<<<NTILES_, 256, 0, stream>>>(gM, gF, itemsM, itemsF, pm, partials);
    reduce_k<<<1, 1024, 0, stream>>>(partials, out);
}